// Round 16
// baseline (662.112 us; speedup 1.0000x reference)
//
#include <hip/hip_runtime.h>
#include <hip/hip_bf16.h>

typedef __attribute__((ext_vector_type(4))) short short4_t;
typedef __attribute__((ext_vector_type(4))) float f32x4;

constexpr int NMB = 256;

#if __has_builtin(__builtin_amdgcn_mfma_f32_16x16x16bf16_1k)
#define MFMA16(a, b, c) __builtin_amdgcn_mfma_f32_16x16x16bf16_1k(a, b, c, 0, 0, 0)
#else
__device__ inline f32x4 mfma16_asm(short4_t a, short4_t b, f32x4 c) {
    asm volatile("v_mfma_f32_16x16x16_bf16 %0, %1, %2, %0\n\ts_nop 7\n\ts_nop 7"
                 : "+v"(c) : "v"(a), "v"(b));
    return c;
}
#define MFMA16(a, b, c) mfma16_asm(a, b, c)
#endif

#define TR_READ(dst, addr, IMM) \
    asm volatile("ds_read_b64_tr_b16 %0, %1 offset:" IMM : "=&v"(dst) : "v"(addr) : "memory")

union U2S4 { unsigned u[2]; short4_t s; };
union FI { float f; int i; };

__device__ inline unsigned pkbf(float a, float b) {
    union { __hip_bfloat162 h; unsigned u; } c;
    c.h = __float22bfloat162_rn(make_float2(a, b));
    return c.u;
}
__device__ inline short4_t pk4(float a, float b, float c, float d) {
    U2S4 u; u.u[0] = pkbf(a, b); u.u[1] = pkbf(c, d); return u.s;
}
// all-VALU 16-lane sum reduce: quad_perm xor1, xor2, then row_ror 4, 8
__device__ inline float dpp16(float x) {
    FI v; v.f = x; FI t;
    t.i = __builtin_amdgcn_update_dpp(0, v.i, 0xB1, 0xf, 0xf, true);  v.f += t.f;
    t.i = __builtin_amdgcn_update_dpp(0, v.i, 0x4E, 0xf, 0xf, true);  v.f += t.f;
    t.i = __builtin_amdgcn_update_dpp(0, v.i, 0x124, 0xf, 0xf, true); v.f += t.f;
    t.i = __builtin_amdgcn_update_dpp(0, v.i, 0x128, 0xf, 0xf, true); v.f += t.f;
    return v.f;
}
// raw barrier: LDS writes visible, global loads stay in flight
__device__ inline void bar() {
    __builtin_amdgcn_sched_barrier(0);
    asm volatile("s_waitcnt lgkmcnt(0)" ::: "memory");
    __builtin_amdgcn_s_barrier();
    __builtin_amdgcn_sched_barrier(0);
}

__global__ __launch_bounds__(256) void ttt_scan(
    const float* __restrict__ gXQ, const float* __restrict__ gXK,
    const float* __restrict__ gXV, const float* __restrict__ gETA,
    const float* __restrict__ gW1, const float* __restrict__ gB1,
    const float* __restrict__ gLNW, const float* __restrict__ gLNB,
    float* __restrict__ gOUT)
{
    __shared__ __align__(16) short sGt[1024];      // g, K=16 4x16 tr-tiles [jblk][nblk]
    __shared__ __align__(16) short sXKe[1024];     // -le*xk, same tiling
    __shared__ __align__(16) float sZ1[16 * 68];
    __shared__ __align__(16) float sZb[16 * 68];

    const int t  = threadIdx.x;
    const int s  = t >> 4;
    const int dt = t & 15;
    const int lane = t & 63;
    const int w  = t >> 6;
    const int G  = lane >> 4;
    const int l15 = lane & 15;
    const int bh = blockIdx.x, b = bh >> 3, h = bh & 7;

    const float* xqg = gXQ + (size_t)bh * (NMB * 1024);
    const float* xkg = gXK + (size_t)bh * (NMB * 1024);
    const float* xvg = gXV + (size_t)bh * (NMB * 1024);
    const float* etg = gETA + (size_t)bh * (NMB * 256);

    // W state: wave w owns COLUMNS [16w,16w+16) as 4 k-tile C-fragments.
    // C layout == B layout (k==row) [R13-verified]; WB[kt] feeds MFMA1 directly.
    f32x4 Wacc[4]; short4_t WB[4];
#pragma unroll
    for (int kt = 0; kt < 4; ++kt) {
#pragma unroll
        for (int r = 0; r < 4; ++r)
            Wacc[kt][r] = gW1[h * 4096 + (16 * kt + 4 * G + r) * 64 + 16 * w + l15];
        WB[kt] = pk4(Wacc[kt][0], Wacc[kt][1], Wacc[kt][2], Wacc[kt][3]);
    }
    float b1v = gB1[h * 64 + 16 * w + l15];

    // LN params in thread layout
    const float4 gam = *(const float4*)&gLNW[h * 64 + dt * 4];
    const float4 bet = *(const float4*)&gLNB[h * 64 + dt * 4];
    const float ga[4] = {gam.x, gam.y, gam.z, gam.w};
    const float ba[4] = {bet.x, bet.y, bet.z, bet.w};
    float c1a[4], gba[4];
    float sc1 = 0.f;
#pragma unroll
    for (int c = 0; c < 4; ++c) {
        c1a[c] = ga[c] * ga[c];
        gba[c] = ga[c] * ba[c];
        sc1 += c1a[c];
    }
    sc1 = dpp16(sc1);

    // ---- prologue: minibatch 0 ----
    float4 pq = *(const float4*)&xqg[t * 4];
    float4 pk = *(const float4*)&xkg[t * 4];
    float4 pv = *(const float4*)&xvg[t * 4];
    // wave-layout A-frag sources for m=0
    short4_t ak[4], aq[4];
#pragma unroll
    for (int kt = 0; kt < 4; ++kt) {
        const f32x4 fk = *(const f32x4*)&xkg[l15 * 64 + 16 * kt + 4 * G];
        const f32x4 fq = *(const f32x4*)&xqg[l15 * 64 + 16 * kt + 4 * G];
        ak[kt] = pk4(fk[0], fk[1], fk[2], fk[3]);
        aq[kt] = pk4(fq[0], fq[1], fq[2], fq[3]);
    }
    f32x4 fkn[4], fqn[4];
    // eta(0) pieces (direct global, no LDS staging)
    f32x4 ev4c = *(const f32x4*)&etg[l15 * 16 + 4 * G];
    f32x4 lvc  = *(const f32x4*)&etg[240 + 4 * G];
    float le_sc = etg[240 + s];
    f32x4 ev4n, lvn; float le_sn;

    float t2c[4];
    float S5c;
    {
        const float pva[4] = {pv.x, pv.y, pv.z, pv.w};
        const float pka_[4] = {pk.x, pk.y, pk.z, pk.w};
        float s5 = 0.f;
#pragma unroll
        for (int c = 0; c < 4; ++c) {
            t2c[c] = fmaf(-ga[c], pva[c] - pka_[c], gba[c]);
            s5 += t2c[c];
        }
        S5c = dpp16(s5);
    }
    float4 pkc = pk;        // xk(m) for phase A's sXKe staging
    float4 pq_out = pq;     // xq(m) for output
    float4 pq_prev_out;

    __syncthreads();

#pragma unroll 1
    for (int m = 0; m < NMB; ++m) {
        // ======== PHASE A: MFMA1 + AttnT + sXKe staging; issue all m+1 prefetch ========
        if (m + 1 < NMB) {
            const size_t o = (size_t)(m + 1) * 1024;
            pq = *(const float4*)&xqg[o + t * 4];
            pk = *(const float4*)&xkg[o + t * 4];
            pv = *(const float4*)&xvg[o + t * 4];
            const size_t ow = o + l15 * 64 + 4 * G;
#pragma unroll
            for (int kt = 0; kt < 4; ++kt) {
                fkn[kt] = *(const f32x4*)&xkg[ow + 16 * kt];
                fqn[kt] = *(const f32x4*)&xqg[ow + 16 * kt];
            }
            const size_t oe = (size_t)(m + 1) * 256;
            ev4n  = *(const f32x4*)&etg[oe + l15 * 16 + 4 * G];
            lvn   = *(const f32x4*)&etg[oe + 240 + 4 * G];
            le_sn = etg[oe + 240 + s];
        }

        // Z1/Zq n-tile w from register WB and register A-frags (no LDS at phase head)
        f32x4 z1, zq;
        z1[0]=b1v; z1[1]=b1v; z1[2]=b1v; z1[3]=b1v;
        zq = z1;
#pragma unroll
        for (int kt = 0; kt < 4; ++kt) z1 = MFMA16(ak[kt], WB[kt], z1);
#pragma unroll
        for (int kt = 0; kt < 4; ++kt) zq = MFMA16(aq[kt], WB[kt], zq);
#pragma unroll
        for (int r = 0; r < 4; ++r) sZ1[(4 * G + r) * 68 + 16 * w + l15] = z1[r];

        // AttnT = xk @ xq^T (swapped operands): slot i holds Attn[l15][4G+i]
        f32x4 at; at[0]=0.f; at[1]=0.f; at[2]=0.f; at[3]=0.f;
#pragma unroll
        for (int kt = 0; kt < 4; ++kt) at = MFMA16(ak[kt], aq[kt], at);

        // sXKe staging for THIS step (le from register, pkc regs; read in phase C)
        {
            const int tb = (s >> 2) * 256 + (dt >> 2) * 64 + (s & 3) * 16 + (dt & 3) * 4;
            U2S4 kp; kp.u[0]=pkbf(-le_sc*pkc.x,-le_sc*pkc.y);
                     kp.u[1]=pkbf(-le_sc*pkc.z,-le_sc*pkc.w);
            *(short4_t*)&sXKe[tb] = kp.s;
        }
        bar();   // (C) sZ1, sXKe visible

        // ======== PHASE B: LN-bwd -> g ; deferred LN-fwd + output (7 parallel chains) ====
        f32x4 z = *(f32x4*)&sZ1[s * 68 + dt * 4];
        f32x4 zbr;
        if (m > 0) zbr = *(f32x4*)&sZb[s * 68 + dt * 4];
        float S1=0.f,S2=0.f,S3=0.f,S4=0.f,S6=0.f;
#pragma unroll
        for (int c = 0; c < 4; ++c) {
            const float zc = z[c], c1z = c1a[c] * zc;
            S1 += zc;  S2 = fmaf(zc, zc, S2);
            S3 += c1z; S4 = fmaf(c1z, zc, S4);
            S6 = fmaf(t2c[c], zc, S6);
        }
        float T1 = 0.f, T2 = 0.f;
        if (m > 0) {
#pragma unroll
            for (int c = 0; c < 4; ++c) { T1 += zbr[c]; T2 = fmaf(zbr[c], zbr[c], T2); }
        }
        S1 = dpp16(S1); S2 = dpp16(S2); S3 = dpp16(S3);
        S4 = dpp16(S4); S6 = dpp16(S6);
        if (m > 0) { T1 = dpp16(T1); T2 = dpp16(T2); }

        const float mu   = S1 * (1.f / 64.f);
        const float rstd = rsqrtf(S2 * (1.f / 64.f) - mu * mu + 1e-6f);
        const float r1 = rstd * (S3 - mu * sc1) + S5c;
        const float r2 = rstd * rstd * (S4 - 2.f * mu * S3 + mu * mu * sc1)
                       + rstd * (S6 - mu * S5c);
        const float cf = rstd * (1.f / 64.f);
        float g[4];
#pragma unroll
        for (int c = 0; c < 4; ++c) {
            const float xh = (z[c] - mu) * rstd;
            const float gx = fmaf(c1a[c], xh, t2c[c]);
            g[c] = (fmaf(64.f, gx, -r1) - xh * r2) * cf;
        }
        {
            const int tb = (s >> 2) * 256 + (dt >> 2) * 64 + (s & 3) * 16 + (dt & 3) * 4;
            U2S4 gp; gp.u[0]=pkbf(g[0],g[1]); gp.u[1]=pkbf(g[2],g[3]);
            *(short4_t*)&sGt[tb] = gp.s;
        }
        if (m > 0) {
            const float mu2   = T1 * (1.f / 64.f);
            const float rstd2 = rsqrtf(T2 * (1.f / 64.f) - mu2 * mu2 + 1e-6f);
            const float pqa[4] = {pq_prev_out.x, pq_prev_out.y, pq_prev_out.z, pq_prev_out.w};
            float o[4];
#pragma unroll
            for (int c = 0; c < 4; ++c)
                o[c] = pqa[c] + fmaf(ga[c], (zbr[c] - mu2) * rstd2, ba[c]);
            const size_t oi = ((size_t)b * 4096 + (size_t)(m - 1) * 16 + s) * 512 + h * 64 + dt * 4;
            *(float4*)&gOUT[oi] = make_float4(o[0], o[1], o[2], o[3]);
        }
        bar();   // (D) sGt visible

        // ======== PHASE C: MFMA2 (W cols in-register) + staging ========
        const unsigned kbX = (unsigned)(size_t)&sXKe[0] + 512u * G + 8u * l15;
        const unsigned kbG = (unsigned)(size_t)&sGt[0] + 512u * G + 128u * (unsigned)w + 8u * l15;
        short4_t aXK0, aXK1, aXK2, aXK3, bg;
        TR_READ(aXK0, kbX, "0");
        TR_READ(aXK1, kbX, "128");
        TR_READ(aXK2, kbX, "256");
        TR_READ(aXK3, kbX, "384");
        TR_READ(bg,   kbG, "0");
        // aE built in-register from AttnT: slot i = -eta[l15][4G+i]*(1+at[i]) masked tril
        float ex[4];
#pragma unroll
        for (int i = 0; i < 4; ++i)
            ex[i] = (4 * G + i <= l15) ? -ev4c[i] * (1.f + at[i]) : 0.f;
        const short4_t aE = pk4(ex[0], ex[1], ex[2], ex[3]);
        U2S4 aL;
        aL.u[0] = pkbf(-lvc[0], -lvc[1]);
        aL.u[1] = pkbf(-lvc[2], -lvc[3]);
        asm volatile("s_waitcnt lgkmcnt(0)" ::: "memory");
        __builtin_amdgcn_sched_barrier(0);

        Wacc[0] = MFMA16(aXK0, bg, Wacc[0]);
        Wacc[1] = MFMA16(aXK1, bg, Wacc[1]);
        Wacc[2] = MFMA16(aXK2, bg, Wacc[2]);
        Wacc[3] = MFMA16(aXK3, bg, Wacc[3]);
        f32x4 zb = MFMA16(aE, bg, zq);
        {
            f32x4 d0; d0[0]=0.f; d0[1]=0.f; d0[2]=0.f; d0[3]=0.f;
            d0 = MFMA16(aL.s, bg, d0);
            b1v += d0[0];
        }
        // repack W C-frags -> B-frags in registers
#pragma unroll
        for (int kt = 0; kt < 4; ++kt)
            WB[kt] = pk4(Wacc[kt][0], Wacc[kt][1], Wacc[kt][2], Wacc[kt][3]);
#pragma unroll
        for (int r = 0; r < 4; ++r) sZb[(4 * G + r) * 68 + 16 * w + l15] = zb[r];

        // STAGE(m+1): pack A-frags from prefetched wave-layout regs; rotate eta/t2c/S5
        if (m + 1 < NMB) {
#pragma unroll
            for (int kt = 0; kt < 4; ++kt) {
                ak[kt] = pk4(fkn[kt][0], fkn[kt][1], fkn[kt][2], fkn[kt][3]);
                aq[kt] = pk4(fqn[kt][0], fqn[kt][1], fqn[kt][2], fqn[kt][3]);
            }
            float s5 = 0.f;
#pragma unroll
            for (int c = 0; c < 4; ++c) {
                const float pva[4] = {pv.x, pv.y, pv.z, pv.w};
                const float pka_[4] = {pk.x, pk.y, pk.z, pk.w};
                t2c[c] = fmaf(-ga[c], pva[c] - pka_[c], gba[c]);
                s5 += t2c[c];
            }
            S5c = dpp16(s5);
            pkc = pk;
            ev4c = ev4n; lvc = lvn; le_sc = le_sn;
        }
        pq_prev_out = pq_out;
        pq_out = pq;
        bar();   // (E) sZb visible
    }

    // epilogue: deferred output for m = NMB-1
    {
        f32x4 zbr = *(f32x4*)&sZb[s * 68 + dt * 4];
        float T1 = 0.f, T2 = 0.f;
#pragma unroll
        for (int c = 0; c < 4; ++c) { T1 += zbr[c]; T2 = fmaf(zbr[c], zbr[c], T2); }
        T1 = dpp16(T1); T2 = dpp16(T2);
        const float mu2   = T1 * (1.f / 64.f);
        const float rstd2 = rsqrtf(T2 * (1.f / 64.f) - mu2 * mu2 + 1e-6f);
        const float pqa[4] = {pq_prev_out.x, pq_prev_out.y, pq_prev_out.z, pq_prev_out.w};
        float o[4];
#pragma unroll
        for (int c = 0; c < 4; ++c)
            o[c] = pqa[c] + fmaf(ga[c], (zbr[c] - mu2) * rstd2, ba[c]);
        const size_t oi = ((size_t)b * 4096 + (size_t)(NMB - 1) * 16 + s) * 512 + h * 64 + dt * 4;
        *(float4*)&gOUT[oi] = make_float4(o[0], o[1], o[2], o[3]);
    }
}

extern "C" void kernel_launch(void* const* d_in, const int* in_sizes, int n_in,
                              void* d_out, int out_size, void* d_ws, size_t ws_size,
                              hipStream_t stream) {
    const float* XQ  = (const float*)d_in[0];
    const float* XK  = (const float*)d_in[1];
    const float* XV  = (const float*)d_in[2];
    const float* ETA = (const float*)d_in[3];
    const float* W1  = (const float*)d_in[4];
    const float* B1  = (const float*)d_in[5];
    const float* LNW = (const float*)d_in[6];
    const float* LNB = (const float*)d_in[7];
    float* OUT = (float*)d_out;

    const int n_chains = in_sizes[0] / (NMB * 1024);   // B*nh = 64
    ttt_scan<<<n_chains, 256, 0, stream>>>(XQ, XK, XV, ETA, W1, B1, LNW, LNB, OUT);
}

// Round 17
// 311.904 us; speedup vs baseline: 2.1228x; 2.1228x over previous
//
#include <hip/hip_runtime.h>
#include <hip/hip_bf16.h>

typedef __attribute__((ext_vector_type(4))) short short4_t;
typedef __attribute__((ext_vector_type(4))) float f32x4;

constexpr int NMB = 256;

#if __has_builtin(__builtin_amdgcn_mfma_f32_16x16x16bf16_1k)
#define MFMA16(a, b, c) __builtin_amdgcn_mfma_f32_16x16x16bf16_1k(a, b, c, 0, 0, 0)
#else
__device__ inline f32x4 mfma16_asm(short4_t a, short4_t b, f32x4 c) {
    asm volatile("v_mfma_f32_16x16x16_bf16 %0, %1, %2, %0\n\ts_nop 7\n\ts_nop 7"
                 : "+v"(c) : "v"(a), "v"(b));
    return c;
}
#define MFMA16(a, b, c) mfma16_asm(a, b, c)
#endif

#define TR_READ(dst, addr, IMM) \
    asm volatile("ds_read_b64_tr_b16 %0, %1 offset:" IMM : "=&v"(dst) : "v"(addr) : "memory")

union U2S4 { unsigned u[2]; short4_t s; };
union FI { float f; int i; };

__device__ inline unsigned pkbf(float a, float b) {
    union { __hip_bfloat162 h; unsigned u; } c;
    c.h = __float22bfloat162_rn(make_float2(a, b));
    return c.u;
}
__device__ inline short4_t pk4(float a, float b, float c, float d) {
    U2S4 u; u.u[0] = pkbf(a, b); u.u[1] = pkbf(c, d); return u.s;
}
// all-VALU 16-lane sum reduce: quad_perm xor1, xor2, then row_ror 4, 8
__device__ inline float dpp16(float x) {
    FI v; v.f = x; FI t;
    t.i = __builtin_amdgcn_update_dpp(0, v.i, 0xB1, 0xf, 0xf, true);  v.f += t.f;
    t.i = __builtin_amdgcn_update_dpp(0, v.i, 0x4E, 0xf, 0xf, true);  v.f += t.f;
    t.i = __builtin_amdgcn_update_dpp(0, v.i, 0x124, 0xf, 0xf, true); v.f += t.f;
    t.i = __builtin_amdgcn_update_dpp(0, v.i, 0x128, 0xf, 0xf, true); v.f += t.f;
    return v.f;
}
// raw barrier: LDS writes visible, global loads stay in flight
__device__ inline void bar() {
    __builtin_amdgcn_sched_barrier(0);
    asm volatile("s_waitcnt lgkmcnt(0)" ::: "memory");
    __builtin_amdgcn_s_barrier();
    __builtin_amdgcn_sched_barrier(0);
}

__global__ __launch_bounds__(256) void ttt_scan(
    const float* __restrict__ gXQ, const float* __restrict__ gXK,
    const float* __restrict__ gXV, const float* __restrict__ gETA,
    const float* __restrict__ gW1, const float* __restrict__ gB1,
    const float* __restrict__ gLNW, const float* __restrict__ gLNB,
    float* __restrict__ gOUT)
{
    __shared__ __align__(16) short bxk[2][16 * 72];  // xk bf16, parity-buffered
    __shared__ __align__(16) short bxq[2][16 * 72];  // xq bf16, parity-buffered
    __shared__ __align__(16) short sGt[1024];        // g, K=16 4x16 tr-tiles
    __shared__ __align__(16) short sXKe[2][1024];    // -le*xk, parity-buffered
    __shared__ __align__(16) float sZ1[16 * 68];
    __shared__ __align__(16) float sZb[16 * 68];

    const int t  = threadIdx.x;
    const int s  = t >> 4;
    const int dt = t & 15;
    const int lane = t & 63;
    const int w  = t >> 6;
    const int G  = lane >> 4;
    const int l15 = lane & 15;
    const int bh = blockIdx.x, b = bh >> 3, h = bh & 7;

    const float* xqg = gXQ + (size_t)bh * (NMB * 1024);
    const float* xkg = gXK + (size_t)bh * (NMB * 1024);
    const float* xvg = gXV + (size_t)bh * (NMB * 1024);
    const float* etg = gETA + (size_t)bh * (NMB * 256);

    // W state: wave w owns COLUMNS [16w,16w+16) as 4 k-tile C-fragments.
    // C layout == B layout (k==row) [R13-verified]; WB[kt] feeds MFMA1 directly.
    f32x4 Wacc[4]; short4_t WB[4];
#pragma unroll
    for (int kt = 0; kt < 4; ++kt) {
#pragma unroll
        for (int r = 0; r < 4; ++r)
            Wacc[kt][r] = gW1[h * 4096 + (16 * kt + 4 * G + r) * 64 + 16 * w + l15];
        WB[kt] = pk4(Wacc[kt][0], Wacc[kt][1], Wacc[kt][2], Wacc[kt][3]);
    }
    float b1v = gB1[h * 64 + 16 * w + l15];

    // LN params in thread layout
    const float4 gam = *(const float4*)&gLNW[h * 64 + dt * 4];
    const float4 bet = *(const float4*)&gLNB[h * 64 + dt * 4];
    const float ga[4] = {gam.x, gam.y, gam.z, gam.w};
    const float ba[4] = {bet.x, bet.y, bet.z, bet.w};
    float c1a[4], gba[4];
    float sc1 = 0.f;
#pragma unroll
    for (int c = 0; c < 4; ++c) {
        c1a[c] = ga[c] * ga[c];
        gba[c] = ga[c] * ba[c];
        sc1 += c1a[c];
    }
    sc1 = dpp16(sc1);

    // ---- prologue: minibatch 0 ----
    float4 pq = *(const float4*)&xqg[t * 4];
    float4 pk = *(const float4*)&xkg[t * 4];
    float4 pv = *(const float4*)&xvg[t * 4];
    // eta(0) pieces in registers (no LDS)
    f32x4 ev4c = *(const f32x4*)&etg[l15 * 16 + 4 * G];
    f32x4 lvc  = *(const f32x4*)&etg[240 + 4 * G];
    float le_sc = etg[240 + s];
    f32x4 ev4n, lvn; float le_sn;

    { U2S4 u_; u_.u[0]=pkbf(pk.x,pk.y); u_.u[1]=pkbf(pk.z,pk.w);
      *(short4_t*)&bxk[0][s * 72 + dt * 4] = u_.s; }
    { U2S4 u_; u_.u[0]=pkbf(pq.x,pq.y); u_.u[1]=pkbf(pq.z,pq.w);
      *(short4_t*)&bxq[0][s * 72 + dt * 4] = u_.s; }
    float t2c[4];
    float S5c;
    {
        const float pva[4] = {pv.x, pv.y, pv.z, pv.w};
        const float pka_[4] = {pk.x, pk.y, pk.z, pk.w};
        float s5 = 0.f;
#pragma unroll
        for (int c = 0; c < 4; ++c) {
            t2c[c] = fmaf(-ga[c], pva[c] - pka_[c], gba[c]);
            s5 += t2c[c];
        }
        S5c = dpp16(s5);
    }
    float4 pkc = pk;        // xk(m) for phase A's sXKe staging
    float4 pq_out = pq;     // xq(m) for output
    float4 pq_prev_out;

    __syncthreads();

#pragma unroll 1
    for (int m = 0; m < NMB; ++m) {
        const int p = m & 1;

        // ======== PHASE A: MFMA1 + AttnT + sXKe[p] staging; issue m+1 prefetch ========
        if (m + 1 < NMB) {
            const size_t o = (size_t)(m + 1) * 1024 + t * 4;
            pq = *(const float4*)&xqg[o];
            pk = *(const float4*)&xkg[o];
            pv = *(const float4*)&xvg[o];
            const size_t oe = (size_t)(m + 1) * 256;
            ev4n  = *(const f32x4*)&etg[oe + l15 * 16 + 4 * G];
            lvn   = *(const f32x4*)&etg[oe + 240 + 4 * G];
            le_sn = etg[oe + 240 + s];
        }

        // A-frags: A[m=l15][k=16kt+4G..+3] from bxk[p]/bxq[p] (b64 reads)
        short4_t ak[4], aq[4];
#pragma unroll
        for (int kt = 0; kt < 4; ++kt) {
            ak[kt] = *(const short4_t*)&bxk[p][l15 * 72 + 16 * kt + 4 * G];
            aq[kt] = *(const short4_t*)&bxq[p][l15 * 72 + 16 * kt + 4 * G];
        }
        // Z1/Zq n-tile w from register WB
        f32x4 z1, zq;
        z1[0]=b1v; z1[1]=b1v; z1[2]=b1v; z1[3]=b1v;
        zq = z1;
#pragma unroll
        for (int kt = 0; kt < 4; ++kt) z1 = MFMA16(ak[kt], WB[kt], z1);
#pragma unroll
        for (int kt = 0; kt < 4; ++kt) zq = MFMA16(aq[kt], WB[kt], zq);
#pragma unroll
        for (int r = 0; r < 4; ++r) sZ1[(4 * G + r) * 68 + 16 * w + l15] = z1[r];

        // AttnT = xk @ xq^T (swapped operands): slot i holds Attn[l15][4G+i]
        f32x4 at; at[0]=0.f; at[1]=0.f; at[2]=0.f; at[3]=0.f;
#pragma unroll
        for (int kt = 0; kt < 4; ++kt) at = MFMA16(ak[kt], aq[kt], at);

        // sXKe[p] staging for THIS step (le_sc + pkc regs; read in phase C)
        {
            const int tb = (s >> 2) * 256 + (dt >> 2) * 64 + (s & 3) * 16 + (dt & 3) * 4;
            U2S4 kp; kp.u[0]=pkbf(-le_sc*pkc.x,-le_sc*pkc.y);
                     kp.u[1]=pkbf(-le_sc*pkc.z,-le_sc*pkc.w);
            *(short4_t*)&sXKe[p][tb] = kp.s;
        }
        bar();   // (C) sZ1, sXKe[p] visible

        // ======== PHASE B: LN-bwd -> g ; deferred output ; STAGE m+1 ========
        f32x4 z = *(f32x4*)&sZ1[s * 68 + dt * 4];
        f32x4 zbr;
        if (m > 0) zbr = *(f32x4*)&sZb[s * 68 + dt * 4];
        float S1=0.f,S2=0.f,S3=0.f,S4=0.f,S6=0.f;
#pragma unroll
        for (int c = 0; c < 4; ++c) {
            const float zc = z[c], c1z = c1a[c] * zc;
            S1 += zc;  S2 = fmaf(zc, zc, S2);
            S3 += c1z; S4 = fmaf(c1z, zc, S4);
            S6 = fmaf(t2c[c], zc, S6);
        }
        float T1 = 0.f, T2 = 0.f;
        if (m > 0) {
#pragma unroll
            for (int c = 0; c < 4; ++c) { T1 += zbr[c]; T2 = fmaf(zbr[c], zbr[c], T2); }
        }
        S1 = dpp16(S1); S2 = dpp16(S2); S3 = dpp16(S3);
        S4 = dpp16(S4); S6 = dpp16(S6);
        if (m > 0) { T1 = dpp16(T1); T2 = dpp16(T2); }

        const float mu   = S1 * (1.f / 64.f);
        const float rstd = rsqrtf(S2 * (1.f / 64.f) - mu * mu + 1e-6f);
        const float r1 = rstd * (S3 - mu * sc1) + S5c;
        const float r2 = rstd * rstd * (S4 - 2.f * mu * S3 + mu * mu * sc1)
                       + rstd * (S6 - mu * S5c);
        const float cf = rstd * (1.f / 64.f);
        float g[4];
#pragma unroll
        for (int c = 0; c < 4; ++c) {
            const float xh = (z[c] - mu) * rstd;
            const float gx = fmaf(c1a[c], xh, t2c[c]);
            g[c] = (fmaf(64.f, gx, -r1) - xh * r2) * cf;
        }
        {
            const int tb = (s >> 2) * 256 + (dt >> 2) * 64 + (s & 3) * 16 + (dt & 3) * 4;
            U2S4 gp; gp.u[0]=pkbf(g[0],g[1]); gp.u[1]=pkbf(g[2],g[3]);
            *(short4_t*)&sGt[tb] = gp.s;
        }
        if (m > 0) {
            const float mu2   = T1 * (1.f / 64.f);
            const float rstd2 = rsqrtf(T2 * (1.f / 64.f) - mu2 * mu2 + 1e-6f);
            const float pqa[4] = {pq_prev_out.x, pq_prev_out.y, pq_prev_out.z, pq_prev_out.w};
            float o[4];
#pragma unroll
            for (int c = 0; c < 4; ++c)
                o[c] = pqa[c] + fmaf(ga[c], (zbr[c] - mu2) * rstd2, ba[c]);
            const size_t oi = ((size_t)b * 4096 + (size_t)(m - 1) * 16 + s) * 512 + h * 64 + dt * 4;
            *(float4*)&gOUT[oi] = make_float4(o[0], o[1], o[2], o[3]);
        }

        // STAGE(m+1): bxk[p^1]/bxq[p^1]; rotate t2c/S5c/pkc/le_sc/pq_out
        if (m + 1 < NMB) {
            { U2S4 u_; u_.u[0]=pkbf(pk.x,pk.y); u_.u[1]=pkbf(pk.z,pk.w);
              *(short4_t*)&bxk[p ^ 1][s * 72 + dt * 4] = u_.s; }
            { U2S4 u_; u_.u[0]=pkbf(pq.x,pq.y); u_.u[1]=pkbf(pq.z,pq.w);
              *(short4_t*)&bxq[p ^ 1][s * 72 + dt * 4] = u_.s; }
            float s5 = 0.f;
#pragma unroll
            for (int c = 0; c < 4; ++c) {
                const float pva[4] = {pv.x, pv.y, pv.z, pv.w};
                const float pka_[4] = {pk.x, pk.y, pk.z, pk.w};
                t2c[c] = fmaf(-ga[c], pva[c] - pka_[c], gba[c]);
                s5 += t2c[c];
            }
            S5c = dpp16(s5);
            pkc = pk;
            le_sc = le_sn;
        }
        pq_prev_out = pq_out;
        pq_out = pq;
        bar();   // (D) sGt + staging visible

        // ======== PHASE C: MFMA2 (W cols in-register); overlaps A(m+1) across waves ====
        const unsigned kbX = (unsigned)(size_t)&sXKe[p][0] + 512u * G + 8u * l15;
        const unsigned kbG = (unsigned)(size_t)&sGt[0] + 512u * G + 128u * (unsigned)w + 8u * l15;
        short4_t aXK0, aXK1, aXK2, aXK3, bg;
        TR_READ(aXK0, kbX, "0");
        TR_READ(aXK1, kbX, "128");
        TR_READ(aXK2, kbX, "256");
        TR_READ(aXK3, kbX, "384");
        TR_READ(bg,   kbG, "0");
        // aE built in-register from AttnT: slot i = -eta[l15][4G+i]*(1+at[i]) masked tril
        float ex[4];
#pragma unroll
        for (int i = 0; i < 4; ++i)
            ex[i] = (4 * G + i <= l15) ? -ev4c[i] * (1.f + at[i]) : 0.f;
        const short4_t aE = pk4(ex[0], ex[1], ex[2], ex[3]);
        U2S4 aL;
        aL.u[0] = pkbf(-lvc[0], -lvc[1]);
        aL.u[1] = pkbf(-lvc[2], -lvc[3]);
        asm volatile("s_waitcnt lgkmcnt(0)" ::: "memory");
        __builtin_amdgcn_sched_barrier(0);

        Wacc[0] = MFMA16(aXK0, bg, Wacc[0]);
        Wacc[1] = MFMA16(aXK1, bg, Wacc[1]);
        Wacc[2] = MFMA16(aXK2, bg, Wacc[2]);
        Wacc[3] = MFMA16(aXK3, bg, Wacc[3]);
        f32x4 zb = MFMA16(aE, bg, zq);
        {
            f32x4 d0; d0[0]=0.f; d0[1]=0.f; d0[2]=0.f; d0[3]=0.f;
            d0 = MFMA16(aL.s, bg, d0);
            b1v += d0[0];
        }
        // repack W C-frags -> B-frags in registers
#pragma unroll
        for (int kt = 0; kt < 4; ++kt)
            WB[kt] = pk4(Wacc[kt][0], Wacc[kt][1], Wacc[kt][2], Wacc[kt][3]);
#pragma unroll
        for (int r = 0; r < 4; ++r) sZb[(4 * G + r) * 68 + 16 * w + l15] = zb[r];

        // rotate eta regs (after their use in aE/aL)
        if (m + 1 < NMB) { ev4c = ev4n; lvc = lvn; }
        // NO barrier here: phase C overlaps phase A of m+1 across waves.
        // Safety: sZb reads happen in B(m+1) after barrier C(m+1); sXKe/bxk/bxq parity.
    }

    // epilogue: deferred output for m = NMB-1
    {
        f32x4 zbr = *(f32x4*)&sZb[s * 68 + dt * 4];
        float T1 = 0.f, T2 = 0.f;
#pragma unroll
        for (int c = 0; c < 4; ++c) { T1 += zbr[c]; T2 = fmaf(zbr[c], zbr[c], T2); }
        T1 = dpp16(T1); T2 = dpp16(T2);
        const float mu2   = T1 * (1.f / 64.f);
        const float rstd2 = rsqrtf(T2 * (1.f / 64.f) - mu2 * mu2 + 1e-6f);
        const float pqa[4] = {pq_prev_out.x, pq_prev_out.y, pq_prev_out.z, pq_prev_out.w};
        float o[4];
#pragma unroll
        for (int c = 0; c < 4; ++c)
            o[c] = pqa[c] + fmaf(ga[c], (zbr[c] - mu2) * rstd2, ba[c]);
        const size_t oi = ((size_t)b * 4096 + (size_t)(NMB - 1) * 16 + s) * 512 + h * 64 + dt * 4;
        *(float4*)&gOUT[oi] = make_float4(o[0], o[1], o[2], o[3]);
    }
}

extern "C" void kernel_launch(void* const* d_in, const int* in_sizes, int n_in,
                              void* d_out, int out_size, void* d_ws, size_t ws_size,
                              hipStream_t stream) {
    const float* XQ  = (const float*)d_in[0];
    const float* XK  = (const float*)d_in[1];
    const float* XV  = (const float*)d_in[2];
    const float* ETA = (const float*)d_in[3];
    const float* W1  = (const float*)d_in[4];
    const float* B1  = (const float*)d_in[5];
    const float* LNW = (const float*)d_in[6];
    const float* LNB = (const float*)d_in[7];
    float* OUT = (float*)d_out;

    const int n_chains = in_sizes[0] / (NMB * 1024);   // B*nh = 64
    ttt_scan<<<n_chains, 256, 0, stream>>>(XQ, XK, XV, ETA, W1, B1, LNW, LNB, OUT);
}